// Round 10
// baseline (92.057 us; speedup 1.0000x reference)
//
#include <hip/hip_runtime.h>
#include <hip/hip_bf16.h>

// Head: B=8, T=2048, D=1024, H=64, fp32 in/out.
#define BB 8
#define TT 2048
#define DD 1024
#define HH 64
#define NROWS (BB*TT)
#define SCALE 45.25483399593904f   // sqrt(2048)
#define SPLIT 4                    // flash split-K factor

typedef __attribute__((ext_vector_type(8))) short short8;
typedef __attribute__((ext_vector_type(4))) float f32x4;

__device__ inline ushort bf16rne(float f) {
    unsigned u = __float_as_uint(f);
    return (ushort)((u + 0x7fffu + ((u >> 16) & 1u)) >> 16);
}
__device__ inline void bfsplit(float f, ushort& hi, ushort& lo) {
    hi = bf16rne(f);
    float fh = __uint_as_float(((unsigned)hi) << 16);
    lo = bf16rne(f - fh);
}
__device__ inline void split_pack8(const float* v, int4& h4, int4& l4) {
    ushort h[8], l[8];
    #pragma unroll
    for (int j = 0; j < 8; ++j) bfsplit(v[j], h[j], l[j]);
    h4 = make_int4((int)(h[0] | ((unsigned)h[1] << 16)), (int)(h[2] | ((unsigned)h[3] << 16)),
                   (int)(h[4] | ((unsigned)h[5] << 16)), (int)(h[6] | ((unsigned)h[7] << 16)));
    l4 = make_int4((int)(l[0] | ((unsigned)l[1] << 16)), (int)(l[2] | ((unsigned)l[3] << 16)),
                   (int)(l[4] | ((unsigned)l[5] << 16)), (int)(l[6] | ((unsigned)l[7] << 16)));
}

// async global->LDS, 16B per lane. LDS dest = wave-uniform base + lane*16.
__device__ inline void gload_lds16(const void* g, void* l) {
    __builtin_amdgcn_global_load_lds(
        (const __attribute__((address_space(1))) unsigned int*)(uintptr_t)(g),
        (__attribute__((address_space(3))) unsigned int*)(uintptr_t)(l),
        16, 0, 0);
}

// ---------------------------------------------------------------------------
// Kernel P: W prep (unchanged). Pre-swizzled chunk-major bf16 hi/lo.
// ---------------------------------------------------------------------------
__global__ __launch_bounds__(256) void wprep_kernel(
        const float* __restrict__ Wq, const float* __restrict__ Wk,
        const float* __restrict__ Wv,
        ushort* __restrict__ WpHi, ushort* __restrict__ WpLo) {
    __shared__ float ws[64 * 65];
    const int m = blockIdx.x >> 4;      // matrix 0..2
    const int c = blockIdx.x & 15;      // k-chunk 0..15
    const float* W = (m == 0) ? Wq : (m == 1) ? Wk : Wv;
    const int tid = threadIdx.x;

    #pragma unroll
    for (int p = 0; p < 4; ++p) {
        int i = tid + p * 256;
        int r = i >> 4, q4 = i & 15;
        float4 v = *(const float4*)(W + (size_t)(c * 64 + r) * 64 + q4 * 4);
        ws[r * 65 + q4 * 4 + 0] = v.x;
        ws[r * 65 + q4 * 4 + 1] = v.y;
        ws[r * 65 + q4 * 4 + 2] = v.z;
        ws[r * 65 + q4 * 4 + 3] = v.w;
    }
    __syncthreads();

    #pragma unroll
    for (int p = 0; p < 2; ++p) {
        int gi = tid + p * 256;
        int nn = gi >> 3, g8 = gi & 7;
        int o  = g8 ^ (nn & 7);
        float v[8];
        #pragma unroll
        for (int j = 0; j < 8; ++j) v[j] = ws[(o * 8 + j) * 65 + nn];
        int4 h4, l4; split_pack8(v, h4, l4);
        size_t base = (size_t)c * 12288 + (size_t)(m * 64 + nn) * 64 + g8 * 8;
        *(int4*)(WpHi + base) = h4;
        *(int4*)(WpLo + base) = l4;
    }
}

// ---------------------------------------------------------------------------
// Kernel A: QKV via MFMA 16x16x32 bf16, 3-pass split precision.
// r10: 2-phase software pipeline (T3-minimum):
//   - B double-buffered in LDS, staged via global_load_lds; next chunk's DMA
//     issued BEFORE this chunk's MFMA -> flies under compute; ONE barrier/chunk.
//   - A tile is WAVE-PRIVATE (4 copies) so its write->read needs no barrier
//     (ds-op ordering within the wave suffices) and can't drain the DMA queue.
//   - BN=96 per block (grid 512x2) so LDS = 2*24KB B + 16KB A = 64KB
//     -> 2 blocks/CU, 8 waves/CU.
// ---------------------------------------------------------------------------
__global__ __launch_bounds__(256) void qkv_kernel(
        const float* __restrict__ x,
        const ushort* __restrict__ WpHi, const ushort* __restrict__ WpLo,
        float* __restrict__ Qo, ushort* __restrict__ KhiP,
        ushort* __restrict__ KloP, ushort* __restrict__ VtP) {
    __shared__ ushort Bhi[2][96 * 64];   // 12 KiB per buffer
    __shared__ ushort Blo[2][96 * 64];
    __shared__ ushort Aws[4][2048];      // per-wave A: hi [0,1024), lo [1024,2048)
    const int tid  = threadIdx.x;
    const int lane = tid & 63;
    const int w    = tid >> 6;
    const int wr   = w >> 1;             // wave row-half (16 rows)
    const int wc   = w & 1;              // wave col-half (48 cols)
    const int n15  = lane & 15;
    const int g    = lane >> 4;
    const int csw  = n15 & 7;
    const int row0 = blockIdx.x * 32;
    const int nh   = blockIdx.y;         // 96-col half of the 192-col B panel

    ushort* myA = Aws[w];

    f32x4 acc[3];
    #pragma unroll
    for (int nt = 0; nt < 3; ++nt) acc[nt] = (f32x4)0.f;

    // x-load geometry: lane covers row wr*16+(lane>>2), 16 cols at (lane&3)*16
    const int arow = wr * 16 + (lane >> 2);
    const int o0   = (lane & 3) << 1;    // first octet of the pair
    const float* xp = x + (size_t)(row0 + arow) * 1024 + o0 * 8;
    const int r7 = arow & 7;
    const int adst0 = (arow & 15) * 64 + ((o0 ^ r7) << 3);
    const int adst1 = (arow & 15) * 64 + (((o0 + 1) ^ r7) << 3);

    // B DMA source (pre-swizzled, linear): this block's 96-row sub-panel
    const ushort* wsh = WpHi + (size_t)nh * 6144 + (size_t)lane * 8;
    const ushort* wsl = WpLo + (size_t)nh * 6144 + (size_t)lane * 8;

    float xv[16];
    // ---- prologue: x(c=0) -> regs, B(c=0) -> buf0 ----
    *(float4*)(xv)      = *(const float4*)(xp);
    *(float4*)(xv + 4)  = *(const float4*)(xp + 4);
    *(float4*)(xv + 8)  = *(const float4*)(xp + 8);
    *(float4*)(xv + 12) = *(const float4*)(xp + 12);
    #pragma unroll
    for (int p = 0; p < 3; ++p) {
        int j = w * 3 + p;               // 12 chunks of 1 KiB per array
        gload_lds16(wsh + j * 512, &Bhi[0][j * 512]);
        gload_lds16(wsl + j * 512, &Blo[0][j * 512]);
    }
    __syncthreads();                     // drain prologue DMA + x loads

    int cur = 0;
    for (int c = 0; c < 16; ++c) {
        // ---- issue NEXT chunk's B-DMA into the other buffer (flies under MFMA)
        if (c + 1 < 16) {
            const ushort* sh = wsh + (size_t)(c + 1) * 12288;
            const ushort* sl = wsl + (size_t)(c + 1) * 12288;
            #pragma unroll
            for (int p = 0; p < 3; ++p) {
                int j = w * 3 + p;
                gload_lds16(sh + j * 512, &Bhi[cur ^ 1][j * 512]);
                gload_lds16(sl + j * 512, &Blo[cur ^ 1][j * 512]);
            }
        }
        // ---- A stage (wave-private): convert xv -> bf16 hi/lo, ds_write ----
        {
            int4 h4, l4;
            split_pack8(xv, h4, l4);
            *(int4*)&myA[adst0]        = h4;
            *(int4*)&myA[1024 + adst0] = l4;
            split_pack8(xv + 8, h4, l4);
            *(int4*)&myA[adst1]        = h4;
            *(int4*)&myA[1024 + adst1] = l4;
        }
        // ---- prefetch x for c+1 (drains at this iteration's end barrier) ----
        if (c + 1 < 16) {
            const float* src = xp + (c + 1) * 64;
            *(float4*)(xv)      = *(const float4*)(src);
            *(float4*)(xv + 4)  = *(const float4*)(src + 4);
            *(float4*)(xv + 8)  = *(const float4*)(src + 8);
            *(float4*)(xv + 12) = *(const float4*)(src + 12);
        }
        // ---- compute on buf[cur] + myA (A ordering = wave-local lgkm) ----
        const ushort* bh = Bhi[cur];
        const ushort* bl = Blo[cur];
        #pragma unroll
        for (int kh = 0; kh < 2; ++kh) {
            const int o = 4 * kh + g;
            short8 afh = *(const short8*)&myA[n15 * 64 + ((o ^ csw) << 3)];
            short8 afl = *(const short8*)&myA[1024 + n15 * 64 + ((o ^ csw) << 3)];
            short8 bfh[3], bfl[3];
            #pragma unroll
            for (int nt = 0; nt < 3; ++nt) {
                int ridx = (wc * 48 + nt * 16 + n15) * 64 + ((o ^ csw) << 3);
                bfh[nt] = *(const short8*)&bh[ridx];
                bfl[nt] = *(const short8*)&bl[ridx];
            }
            #pragma unroll
            for (int nt = 0; nt < 3; ++nt) {
                acc[nt] = __builtin_amdgcn_mfma_f32_16x16x32_bf16(afh, bfh[nt], acc[nt], 0, 0, 0);
                acc[nt] = __builtin_amdgcn_mfma_f32_16x16x32_bf16(afl, bfh[nt], acc[nt], 0, 0, 0);
                acc[nt] = __builtin_amdgcn_mfma_f32_16x16x32_bf16(afh, bfl[nt], acc[nt], 0, 0, 0);
            }
        }
        __syncthreads();                 // ONE barrier: drains next-DMA + swaps
        cur ^= 1;
    }

    // ---- epilogue: row = row0+wr*16+4g+r, col = nh*96+wc*48+nt*16+n15 ----
    const int b  = row0 >> 11;
    const int t0 = row0 & 2047;
    const int mb = row0 + wr * 16 + 4 * g;
    #pragma unroll
    for (int nt = 0; nt < 3; ++nt) {
        const int col = nh * 96 + wc * 48 + nt * 16 + n15;
        const int mat = col >> 6;        // uniform per nt (16-col tiles)
        const int h   = col & 63;
        if (mat == 0) {
            #pragma unroll
            for (int r = 0; r < 4; ++r)
                Qo[(size_t)(mb + r) * 64 + h] = acc[nt][r];
        } else if (mat == 1) {
            #pragma unroll
            for (int r = 0; r < 4; ++r) {
                ushort hi, lo; bfsplit(acc[nt][r], hi, lo);
                KhiP[(size_t)(mb + r) * 64 + h] = hi;
                KloP[(size_t)(mb + r) * 64 + h] = lo;
            }
        } else {
            ushort pk[4];
            #pragma unroll
            for (int r = 0; r < 4; ++r) pk[r] = bf16rne(acc[nt][r]);
            const int tloc = t0 + wr * 16 + 4 * g;
            *(uint2*)&VtP[((size_t)(b * 64 + h)) * 2048 + tloc] =
                make_uint2(pk[0] | ((unsigned)pk[1] << 16),
                           pk[2] | ((unsigned)pk[3] << 16));
        }
    }
}

// ---------------------------------------------------------------------------
// Kernel B: causal flash attention (r9, unchanged): MFMA + DMA-staged LDS +
// split-K x4 (2048 blocks, ~6 blocks/CU).
// ---------------------------------------------------------------------------
__global__ __launch_bounds__(128) void attn_kernel(
        const float* __restrict__ Q, const ushort* __restrict__ Khi,
        const ushort* __restrict__ Klo, const ushort* __restrict__ Vt,
        float* __restrict__ Pacc, float* __restrict__ Pm,
        float* __restrict__ Pl) {
    __shared__ ushort KhiL[64 * 64];   // [key][h ^ ((key&7)<<3)]
    __shared__ ushort KloL[64 * 64];
    __shared__ ushort VtL[64 * 64];    // [h][key ^ ((h&7)<<3)]
    const int tid  = threadIdx.x;
    const int lane = tid & 63;
    const int w    = tid >> 6;
    const int n    = lane & 15;
    const int g    = lane >> 4;
    const int b    = blockIdx.y;
    const int xx   = blockIdx.x;            // 0..255, heavy-first
    const int qt   = 63 - (xx >> 2);
    const int sp   = xx & 3;
    const int q0   = qt * 32;
    const int qmin = q0 + w * 16;
    const int qrow = qmin + n;
    const int csw  = n & 7;
    const int ntiles = (q0 >> 6) + 1;
    const int it0  = (ntiles * sp) >> 2;    // last split owns the diagonal
    const int it1  = (ntiles * (sp + 1)) >> 2;

    short8 qhi0, qhi1, qlo0, qlo1;
    {
        const float* qp = Q + ((size_t)b * TT + qrow) * HH + 8 * g;
        float v0[8], v1[8];
        *(float4*)(v0)     = *(const float4*)(qp);
        *(float4*)(v0 + 4) = *(const float4*)(qp + 4);
        *(float4*)(v1)     = *(const float4*)(qp + 32);
        *(float4*)(v1 + 4) = *(const float4*)(qp + 36);
        #pragma unroll
        for (int j = 0; j < 8; ++j) {
            ushort hi, lo;
            bfsplit(v0[j], hi, lo); qhi0[j] = (short)hi; qlo0[j] = (short)lo;
            bfsplit(v1[j], hi, lo); qhi1[j] = (short)hi; qlo1[j] = (short)lo;
        }
    }

    f32x4 accO[4];
    #pragma unroll
    for (int t = 0; t < 4; ++t) accO[t] = (f32x4)0.f;
    float m = -1e30f, l = 0.f;

    const ushort* gkh = Khi + (size_t)b * TT * HH;
    const ushort* gkl = Klo + (size_t)b * TT * HH;
    const ushort* gvt = Vt + (size_t)b * 64 * TT;

    const int crow = lane >> 3;             // row within 8-row chunk
    const int coct = lane & 7;              // LDS octet position

    for (int it = it0; it < it1; ++it) {
        const int kb = it * 64;
        __syncthreads();                    // prev compute done with LDS
        #pragma unroll
        for (int p = 0; p < 4; ++p) {
            const int cc  = w * 4 + p;      // chunk 0..7
            const int row = (cc << 3) + crow;
            const int soc = coct ^ (row & 7);
            gload_lds16(gkh + (size_t)(kb + row) * HH + (soc << 3), &KhiL[cc << 9]);
            gload_lds16(gkl + (size_t)(kb + row) * HH + (soc << 3), &KloL[cc << 9]);
            gload_lds16(gvt + (size_t)row * TT + kb + (soc << 3),   &VtL[cc << 9]);
        }
        __syncthreads();                    // drains vmcnt -> tiles ready

        f32x4 s4[4];
        #pragma unroll
        for (int s = 0; s < 4; ++s) {
            const int keyl = 16 * s + n;
            const ushort* kbase = &KhiL[keyl << 6];
            const ushort* lbase = &KloL[keyl << 6];
            short8 kh0 = *(const short8*)(kbase + ((g ^ csw) << 3));
            short8 kh1 = *(const short8*)(kbase + (((4 + g) ^ csw) << 3));
            short8 kl0 = *(const short8*)(lbase + ((g ^ csw) << 3));
            short8 kl1 = *(const short8*)(lbase + (((4 + g) ^ csw) << 3));
            f32x4 a = (f32x4)0.f;
            a = __builtin_amdgcn_mfma_f32_16x16x32_bf16(kh0, qhi0, a, 0, 0, 0);
            a = __builtin_amdgcn_mfma_f32_16x16x32_bf16(kh1, qhi1, a, 0, 0, 0);
            a = __builtin_amdgcn_mfma_f32_16x16x32_bf16(kl0, qhi0, a, 0, 0, 0);
            a = __builtin_amdgcn_mfma_f32_16x16x32_bf16(kl1, qhi1, a, 0, 0, 0);
            a = __builtin_amdgcn_mfma_f32_16x16x32_bf16(kh0, qlo0, a, 0, 0, 0);
            a = __builtin_amdgcn_mfma_f32_16x16x32_bf16(kh1, qlo1, a, 0, 0, 0);
            s4[s] = a;
        }

        float sm[16];
        if (kb + 63 > qmin) {               // diagonal tile only
            #pragma unroll
            for (int s = 0; s < 4; ++s)
                #pragma unroll
                for (int r = 0; r < 4; ++r) {
                    int keyg = kb + 16 * s + 4 * g + r;
                    sm[s * 4 + r] = (keyg <= qrow) ? s4[s][r] * SCALE : -1e30f;
                }
        } else {
            #pragma unroll
            for (int s = 0; s < 4; ++s)
                #pragma unroll
                for (int r = 0; r < 4; ++r) sm[s * 4 + r] = s4[s][r] * SCALE;
        }
        float pm = sm[0];
        #pragma unroll
        for (int i = 1; i < 16; ++i) pm = fmaxf(pm, sm[i]);
        pm = fmaxf(pm, __shfl_xor(pm, 16));
        pm = fmaxf(pm, __shfl_xor(pm, 32));
        float mn = fmaxf(m, pm);
        float es = __expf(m - mn);
        float p[16], ps = 0.f;
        #pragma unroll
        for (int i = 0; i < 16; ++i) { p[i] = __expf(sm[i] - mn); ps += p[i]; }
        ps += __shfl_xor(ps, 16);
        ps += __shfl_xor(ps, 32);
        l = l * es + ps;
        m = mn;
        #pragma unroll
        for (int t = 0; t < 4; ++t)
            #pragma unroll
            for (int r = 0; r < 4; ++r) accO[t][r] *= es;

        short8 pf0, pf1;
        #pragma unroll
        for (int j = 0; j < 4; ++j) {
            pf0[j]     = (short)bf16rne(p[0 * 4 + j]);
            pf0[j + 4] = (short)bf16rne(p[1 * 4 + j]);
            pf1[j]     = (short)bf16rne(p[2 * 4 + j]);
            pf1[j + 4] = (short)bf16rne(p[3 * 4 + j]);
        }

        #pragma unroll
        for (int t = 0; t < 4; ++t) {
            const int h = 16 * t + n;
            const ushort* vb = &VtL[h << 6];
            union { int2 d[2]; short8 v; } u0, u1;
            u0.d[0] = *(const int2*)(vb + ((4 * g) ^ (csw << 3)));
            u0.d[1] = *(const int2*)(vb + ((16 + 4 * g) ^ (csw << 3)));
            u1.d[0] = *(const int2*)(vb + ((32 + 4 * g) ^ (csw << 3)));
            u1.d[1] = *(const int2*)(vb + ((48 + 4 * g) ^ (csw << 3)));
            accO[t] = __builtin_amdgcn_mfma_f32_16x16x32_bf16(u0.v, pf0, accO[t], 0, 0, 0);
            accO[t] = __builtin_amdgcn_mfma_f32_16x16x32_bf16(u1.v, pf1, accO[t], 0, 0, 0);
        }
    }

    // ---- write partials (unnormalized) ----
    const size_t brow = (size_t)b * TT + qrow;
    float* pa = Pacc + ((size_t)sp * NROWS + brow) * 64 + 4 * g;
    #pragma unroll
    for (int t = 0; t < 4; ++t)
        *(f32x4*)(pa + 16 * t) = accO[t];
    if (g == 0) {
        Pm[(size_t)sp * NROWS + brow] = m;
        Pl[(size_t)sp * NROWS + brow] = l;
    }
}

// ---------------------------------------------------------------------------
// Kernel C: merge SPLIT partials (unchanged).
// ---------------------------------------------------------------------------
__global__ __launch_bounds__(256) void combine_kernel(
        const float* __restrict__ Pacc, const float* __restrict__ Pm,
        const float* __restrict__ Pl, float* __restrict__ out) {
    const int u    = blockIdx.x * 256 + threadIdx.x;   // 0..65535
    const int row  = u >> 2;
    const int quad = u & 3;

    float ms[SPLIT], ls[SPLIT], M = -1e30f;
    #pragma unroll
    for (int s = 0; s < SPLIT; ++s) {
        ms[s] = Pm[(size_t)s * NROWS + row];
        ls[s] = Pl[(size_t)s * NROWS + row];
        M = fmaxf(M, ms[s]);
    }
    float wgt[SPLIT], den = 0.f;
    #pragma unroll
    for (int s = 0; s < SPLIT; ++s) {
        wgt[s] = __expf(ms[s] - M);
        den += wgt[s] * ls[s];
    }
    const float inv = 1.0f / den;

    float4 o[4];
    #pragma unroll
    for (int i = 0; i < 4; ++i) o[i] = make_float4(0.f, 0.f, 0.f, 0.f);
    #pragma unroll
    for (int s = 0; s < SPLIT; ++s) {
        const float4* a = (const float4*)(Pacc + ((size_t)s * NROWS + row) * 64 + quad * 16);
        #pragma unroll
        for (int i = 0; i < 4; ++i) {
            float4 v = a[i];
            o[i].x += wgt[s] * v.x; o[i].y += wgt[s] * v.y;
            o[i].z += wgt[s] * v.z; o[i].w += wgt[s] * v.w;
        }
    }
    float4* op = (float4*)(out + (size_t)row * 64 + quad * 16);
    #pragma unroll
    for (int i = 0; i < 4; ++i)
        op[i] = make_float4(o[i].x * inv, o[i].y * inv, o[i].z * inv, o[i].w * inv);
}

// ---------------------------------------------------------------------------
extern "C" void kernel_launch(void* const* d_in, const int* in_sizes, int n_in,
                              void* d_out, int out_size, void* d_ws, size_t ws_size,
                              hipStream_t stream) {
    const float* x  = (const float*)d_in[0];
    const float* Wq = (const float*)d_in[1];
    const float* Wk = (const float*)d_in[2];
    const float* Wv = (const float*)d_in[3];
    float* outp = (float*)d_out;

    float*  Qw   = (float*)d_ws;                        // 4 MB
    ushort* KhiP = (ushort*)(Qw + (size_t)NROWS * HH);  // 2 MB
    ushort* KloP = KhiP + (size_t)NROWS * HH;           // 2 MB
    ushort* VtP  = KloP + (size_t)NROWS * HH;           // 2 MB
    ushort* WpHi = VtP + (size_t)NROWS * HH;            // 384 KB
    ushort* WpLo = WpHi + (size_t)3 * 64 * 1024;        // 384 KB
    float*  Pacc = (float*)(WpLo + (size_t)3 * 64 * 1024);      // 16 MB
    float*  Pm   = Pacc + (size_t)SPLIT * NROWS * HH;           // 256 KB
    float*  Pl   = Pm + (size_t)SPLIT * NROWS;                  // 256 KB

    wprep_kernel<<<48, 256, 0, stream>>>(Wq, Wk, Wv, WpHi, WpLo);
    qkv_kernel<<<dim3(NROWS / 32, 2), 256, 0, stream>>>(x, WpHi, WpLo, Qw, KhiP, KloP, VtP);
    attn_kernel<<<dim3(64 * SPLIT, BB), 128, 0, stream>>>(Qw, KhiP, KloP, VtP,
                                                          Pacc, Pm, Pl);
    combine_kernel<<<NROWS * 4 / 256, 256, 0, stream>>>(Pacc, Pm, Pl, outp);
}

// Round 11
// 80.552 us; speedup vs baseline: 1.1428x; 1.1428x over previous
//
#include <hip/hip_runtime.h>
#include <hip/hip_bf16.h>

// Head: B=8, T=2048, D=1024, H=64, fp32 in/out.
#define BB 8
#define TT 2048
#define DD 1024
#define HH 64
#define NROWS (BB*TT)
#define SCALE 45.25483399593904f   // sqrt(2048)
#define SPLIT 4                    // flash split-K factor
#define NC 32                      // qkv k-chunks (BK=32)

typedef __attribute__((ext_vector_type(8))) short short8;
typedef __attribute__((ext_vector_type(4))) float f32x4;

__device__ inline ushort bf16rne(float f) {
    unsigned u = __float_as_uint(f);
    return (ushort)((u + 0x7fffu + ((u >> 16) & 1u)) >> 16);
}
__device__ inline void bfsplit(float f, ushort& hi, ushort& lo) {
    hi = bf16rne(f);
    float fh = __uint_as_float(((unsigned)hi) << 16);
    lo = bf16rne(f - fh);
}
__device__ inline void split_pack8(const float* v, int4& h4, int4& l4) {
    ushort h[8], l[8];
    #pragma unroll
    for (int j = 0; j < 8; ++j) bfsplit(v[j], h[j], l[j]);
    h4 = make_int4((int)(h[0] | ((unsigned)h[1] << 16)), (int)(h[2] | ((unsigned)h[3] << 16)),
                   (int)(h[4] | ((unsigned)h[5] << 16)), (int)(h[6] | ((unsigned)h[7] << 16)));
    l4 = make_int4((int)(l[0] | ((unsigned)l[1] << 16)), (int)(l[2] | ((unsigned)l[3] << 16)),
                   (int)(l[4] | ((unsigned)l[5] << 16)), (int)(l[6] | ((unsigned)l[7] << 16)));
}
__device__ inline void split_pack4(float4 v, uint2& h, uint2& l) {
    ushort h0, h1, h2, h3, l0, l1, l2, l3;
    bfsplit(v.x, h0, l0); bfsplit(v.y, h1, l1);
    bfsplit(v.z, h2, l2); bfsplit(v.w, h3, l3);
    h = make_uint2(h0 | ((unsigned)h1 << 16), h2 | ((unsigned)h3 << 16));
    l = make_uint2(l0 | ((unsigned)l1 << 16), l2 | ((unsigned)l3 << 16));
}

// async global->LDS, 16B per lane. LDS dest = wave-uniform base + lane*16.
__device__ inline void gload_lds16(const void* g, void* l) {
    __builtin_amdgcn_global_load_lds(
        (const __attribute__((address_space(1))) unsigned int*)(uintptr_t)(g),
        (__attribute__((address_space(3))) unsigned int*)(uintptr_t)(l),
        16, 0, 0);
}

// ---------------------------------------------------------------------------
// Kernel P: W prep, r11: BK=32 chunk-major layout with octet^(col&3) swizzle:
//   Wp[c32][col][o'][j] (ushort), o' = o ^ (col&3),
//   element = W[k = c32*32 + o*8 + j][col], col = m*64+nn in 0..191.
// ---------------------------------------------------------------------------
__global__ __launch_bounds__(256) void wprep_kernel(
        const float* __restrict__ Wq, const float* __restrict__ Wk,
        const float* __restrict__ Wv,
        ushort* __restrict__ WpHi, ushort* __restrict__ WpLo) {
    __shared__ float ws[64 * 65];
    const int m = blockIdx.x >> 4;      // matrix 0..2
    const int c16 = blockIdx.x & 15;    // 64-k slab 0..15
    const float* W = (m == 0) ? Wq : (m == 1) ? Wk : Wv;
    const int tid = threadIdx.x;

    #pragma unroll
    for (int p = 0; p < 4; ++p) {
        int i = tid + p * 256;
        int r = i >> 4, q4 = i & 15;
        float4 v = *(const float4*)(W + (size_t)(c16 * 64 + r) * 64 + q4 * 4);
        ws[r * 65 + q4 * 4 + 0] = v.x;
        ws[r * 65 + q4 * 4 + 1] = v.y;
        ws[r * 65 + q4 * 4 + 2] = v.z;
        ws[r * 65 + q4 * 4 + 3] = v.w;
    }
    __syncthreads();

    #pragma unroll
    for (int p = 0; p < 2; ++p) {
        int gi = tid + p * 256;
        int nn = gi >> 3, g8 = gi & 7;  // col-in-slab, k-octet 0..7
        float v[8];
        #pragma unroll
        for (int j = 0; j < 8; ++j) v[j] = ws[(g8 * 8 + j) * 65 + nn];
        int4 h4, l4; split_pack8(v, h4, l4);
        const int c32 = c16 * 2 + (g8 >> 2);
        const int o   = g8 & 3;
        const int col = m * 64 + nn;
        const int op  = o ^ (col & 3);
        size_t base = (size_t)c32 * 6144 + (size_t)col * 32 + (op << 3);
        *(int4*)(WpHi + base) = h4;
        *(int4*)(WpLo + base) = l4;
    }
}

// ---------------------------------------------------------------------------
// Kernel A: QKV via MFMA 16x16x32 bf16, 3-pass split precision.
// r11: one-barrier-per-chunk pipeline, BK=32, BM=32, BN=192:
//   - B double-buffered (2x24KB), staged via global_load_lds issued BEFORE
//     this chunk's compute -> DMA flies under convert+ds_read+MFMA.
//   - A double-buffered block-shared (2x4KB): x prefetched depth-2 in regs
//     (4 floats/thread, unconditional clamped loads), converted into the
//     OTHER A buffer each iteration.
//   - LDS 56KB -> 2 blocks/CU (8 waves/CU). x read exactly once (FETCH ~36MB).
//   - octet^(col&3) swizzle on A and B: every b128 frag read is a bijection
//     over a 1KB window -> conflict-free.
// ---------------------------------------------------------------------------
__global__ __launch_bounds__(256, 2) void qkv_kernel(
        const float* __restrict__ x,
        const ushort* __restrict__ WpHi, const ushort* __restrict__ WpLo,
        float* __restrict__ Qo, ushort* __restrict__ KhiP,
        ushort* __restrict__ KloP, ushort* __restrict__ VtP) {
    __shared__ ushort Ahi[2][32 * 32], Alo[2][32 * 32];     // 2KB/buf each
    __shared__ ushort Bhi[2][192 * 32], Blo[2][192 * 32];   // 12KB/buf each
    const int tid  = threadIdx.x;
    const int lane = tid & 63;
    const int w    = tid >> 6;
    const int n15  = lane & 15;
    const int g    = lane >> 4;
    const int cx   = n15 & 3;            // frag-read XOR constant
    const int row0 = blockIdx.x * 32;

    f32x4 acc[2][3];
    #pragma unroll
    for (int ms = 0; ms < 2; ++ms)
        #pragma unroll
        for (int nt = 0; nt < 3; ++nt) acc[ms][nt] = (f32x4)0.f;

    // x-load geometry: thread owns (row xr, k-quad xq): 4 floats per chunk
    const int xr = tid >> 3, xq = tid & 7;
    const float* xp = x + (size_t)(row0 + xr) * 1024 + xq * 4;
    const int aoct = xq >> 1;
    const int adst = xr * 32 + ((aoct ^ (xr & 3)) << 3) + ((xq & 1) << 2);

    // B DMA: 12 chunks of 1KB per array; wave w owns chunks w*3..w*3+2
    const ushort* wsh = WpHi + (size_t)lane * 8;
    const ushort* wsl = WpLo + (size_t)lane * 8;

    // ---- prologue: establish invariant (xA=chunk c+1, xB=chunk c+2) ----
    float4 x0 = *(const float4*)(xp);            // chunk 0
    float4 xA = *(const float4*)(xp + 32);       // chunk 1
    float4 xB = *(const float4*)(xp + 64);       // chunk 2
    #pragma unroll
    for (int p = 0; p < 3; ++p) {
        int j = w * 3 + p;
        gload_lds16(wsh + j * 512, &Bhi[0][j * 512]);
        gload_lds16(wsl + j * 512, &Blo[0][j * 512]);
    }
    {
        uint2 h, l; split_pack4(x0, h, l);
        *(uint2*)&Ahi[0][adst] = h;
        *(uint2*)&Alo[0][adst] = l;
    }
    __syncthreads();

    int cur = 0;
    for (int c = 0; c < NC; ++c) {
        // ---- prefetch x(c+3) (clamped, unconditional) ----
        const int c3 = (c + 3 < NC) ? c + 3 : NC - 1;
        float4 xN = *(const float4*)(xp + c3 * 32);
        // ---- issue B DMA for chunk c+1 (clamped) into buf[cur^1] ----
        const int c1 = (c + 1 < NC) ? c + 1 : NC - 1;
        {
            const ushort* sh = wsh + (size_t)c1 * 6144;
            const ushort* sl = wsl + (size_t)c1 * 6144;
            #pragma unroll
            for (int p = 0; p < 3; ++p) {
                int j = w * 3 + p;
                gload_lds16(sh + j * 512, &Bhi[cur ^ 1][j * 512]);
                gload_lds16(sl + j * 512, &Blo[cur ^ 1][j * 512]);
            }
        }
        // ---- convert xA (chunk c+1) into A buf[cur^1] ----
        {
            uint2 h, l; split_pack4(xA, h, l);
            *(uint2*)&Ahi[cur ^ 1][adst] = h;
            *(uint2*)&Alo[cur ^ 1][adst] = l;
        }
        // ---- compute chunk c from buf[cur] ----
        short8 afh[2], afl[2], bfh[3], bfl[3];
        #pragma unroll
        for (int ms = 0; ms < 2; ++ms) {
            int ao = (ms * 16 + n15) * 32 + ((g ^ cx) << 3);
            afh[ms] = *(const short8*)&Ahi[cur][ao];
            afl[ms] = *(const short8*)&Alo[cur][ao];
        }
        #pragma unroll
        for (int nt = 0; nt < 3; ++nt) {
            int bo = (w * 48 + nt * 16 + n15) * 32 + ((g ^ cx) << 3);
            bfh[nt] = *(const short8*)&Bhi[cur][bo];
            bfl[nt] = *(const short8*)&Blo[cur][bo];
        }
        #pragma unroll
        for (int nt = 0; nt < 3; ++nt)
            #pragma unroll
            for (int ms = 0; ms < 2; ++ms) {
                acc[ms][nt] = __builtin_amdgcn_mfma_f32_16x16x32_bf16(
                    afh[ms], bfh[nt], acc[ms][nt], 0, 0, 0);
                acc[ms][nt] = __builtin_amdgcn_mfma_f32_16x16x32_bf16(
                    afl[ms], bfh[nt], acc[ms][nt], 0, 0, 0);
                acc[ms][nt] = __builtin_amdgcn_mfma_f32_16x16x32_bf16(
                    afh[ms], bfl[nt], acc[ms][nt], 0, 0, 0);
            }
        __syncthreads();                 // ONE barrier: drains DMA + A writes
        xA = xB; xB = xN; cur ^= 1;
    }

    // ---- epilogue (r9): row = row0+ms*16+4g+r, col = w*48+nt*16+n15 ----
    const int b  = row0 >> 11;
    const int t0 = row0 & 2047;
    #pragma unroll
    for (int nt = 0; nt < 3; ++nt) {
        const int nglob = w * 48 + nt * 16 + n15;
        const int mat = nglob >> 6;      // wave-uniform
        const int h = nglob & 63;
        #pragma unroll
        for (int ms = 0; ms < 2; ++ms) {
            const int mb = row0 + ms * 16 + 4 * g;
            if (mat == 0) {
                #pragma unroll
                for (int r = 0; r < 4; ++r)
                    Qo[(size_t)(mb + r) * 64 + h] = acc[ms][nt][r];
            } else if (mat == 1) {
                #pragma unroll
                for (int r = 0; r < 4; ++r) {
                    ushort hi, lo; bfsplit(acc[ms][nt][r], hi, lo);
                    KhiP[(size_t)(mb + r) * 64 + h] = hi;
                    KloP[(size_t)(mb + r) * 64 + h] = lo;
                }
            } else {
                ushort pk[4];
                #pragma unroll
                for (int r = 0; r < 4; ++r) pk[r] = bf16rne(acc[ms][nt][r]);
                const int tloc = t0 + ms * 16 + 4 * g;
                *(uint2*)&VtP[((size_t)(b * 64 + h)) * 2048 + tloc] =
                    make_uint2(pk[0] | ((unsigned)pk[1] << 16),
                               pk[2] | ((unsigned)pk[3] << 16));
            }
        }
    }
}

// ---------------------------------------------------------------------------
// Kernel B: causal flash attention (r9, unchanged): MFMA + DMA-staged LDS +
// split-K x4 (2048 blocks, ~6 blocks/CU).
// ---------------------------------------------------------------------------
__global__ __launch_bounds__(128) void attn_kernel(
        const float* __restrict__ Q, const ushort* __restrict__ Khi,
        const ushort* __restrict__ Klo, const ushort* __restrict__ Vt,
        float* __restrict__ Pacc, float* __restrict__ Pm,
        float* __restrict__ Pl) {
    __shared__ ushort KhiL[64 * 64];   // [key][h ^ ((key&7)<<3)]
    __shared__ ushort KloL[64 * 64];
    __shared__ ushort VtL[64 * 64];    // [h][key ^ ((h&7)<<3)]
    const int tid  = threadIdx.x;
    const int lane = tid & 63;
    const int w    = tid >> 6;
    const int n    = lane & 15;
    const int g    = lane >> 4;
    const int b    = blockIdx.y;
    const int xx   = blockIdx.x;            // 0..255, heavy-first
    const int qt   = 63 - (xx >> 2);
    const int sp   = xx & 3;
    const int q0   = qt * 32;
    const int qmin = q0 + w * 16;
    const int qrow = qmin + n;
    const int csw  = n & 7;
    const int ntiles = (q0 >> 6) + 1;
    const int it0  = (ntiles * sp) >> 2;    // last split owns the diagonal
    const int it1  = (ntiles * (sp + 1)) >> 2;

    short8 qhi0, qhi1, qlo0, qlo1;
    {
        const float* qp = Q + ((size_t)b * TT + qrow) * HH + 8 * g;
        float v0[8], v1[8];
        *(float4*)(v0)     = *(const float4*)(qp);
        *(float4*)(v0 + 4) = *(const float4*)(qp + 4);
        *(float4*)(v1)     = *(const float4*)(qp + 32);
        *(float4*)(v1 + 4) = *(const float4*)(qp + 36);
        #pragma unroll
        for (int j = 0; j < 8; ++j) {
            ushort hi, lo;
            bfsplit(v0[j], hi, lo); qhi0[j] = (short)hi; qlo0[j] = (short)lo;
            bfsplit(v1[j], hi, lo); qhi1[j] = (short)hi; qlo1[j] = (short)lo;
        }
    }

    f32x4 accO[4];
    #pragma unroll
    for (int t = 0; t < 4; ++t) accO[t] = (f32x4)0.f;
    float m = -1e30f, l = 0.f;

    const ushort* gkh = Khi + (size_t)b * TT * HH;
    const ushort* gkl = Klo + (size_t)b * TT * HH;
    const ushort* gvt = Vt + (size_t)b * 64 * TT;

    const int crow = lane >> 3;             // row within 8-row chunk
    const int coct = lane & 7;              // LDS octet position

    for (int it = it0; it < it1; ++it) {
        const int kb = it * 64;
        __syncthreads();                    // prev compute done with LDS
        #pragma unroll
        for (int p = 0; p < 4; ++p) {
            const int cc  = w * 4 + p;      // chunk 0..7
            const int row = (cc << 3) + crow;
            const int soc = coct ^ (row & 7);
            gload_lds16(gkh + (size_t)(kb + row) * HH + (soc << 3), &KhiL[cc << 9]);
            gload_lds16(gkl + (size_t)(kb + row) * HH + (soc << 3), &KloL[cc << 9]);
            gload_lds16(gvt + (size_t)row * TT + kb + (soc << 3),   &VtL[cc << 9]);
        }
        __syncthreads();                    // drains vmcnt -> tiles ready

        f32x4 s4[4];
        #pragma unroll
        for (int s = 0; s < 4; ++s) {
            const int keyl = 16 * s + n;
            const ushort* kbase = &KhiL[keyl << 6];
            const ushort* lbase = &KloL[keyl << 6];
            short8 kh0 = *(const short8*)(kbase + ((g ^ csw) << 3));
            short8 kh1 = *(const short8*)(kbase + (((4 + g) ^ csw) << 3));
            short8 kl0 = *(const short8*)(lbase + ((g ^ csw) << 3));
            short8 kl1 = *(const short8*)(lbase + (((4 + g) ^ csw) << 3));
            f32x4 a = (f32x4)0.f;
            a = __builtin_amdgcn_mfma_f32_16x16x32_bf16(kh0, qhi0, a, 0, 0, 0);
            a = __builtin_amdgcn_mfma_f32_16x16x32_bf16(kh1, qhi1, a, 0, 0, 0);
            a = __builtin_amdgcn_mfma_f32_16x16x32_bf16(kl0, qhi0, a, 0, 0, 0);
            a = __builtin_amdgcn_mfma_f32_16x16x32_bf16(kl1, qhi1, a, 0, 0, 0);
            a = __builtin_amdgcn_mfma_f32_16x16x32_bf16(kh0, qlo0, a, 0, 0, 0);
            a = __builtin_amdgcn_mfma_f32_16x16x32_bf16(kh1, qlo1, a, 0, 0, 0);
            s4[s] = a;
        }

        float sm[16];
        if (kb + 63 > qmin) {               // diagonal tile only
            #pragma unroll
            for (int s = 0; s < 4; ++s)
                #pragma unroll
                for (int r = 0; r < 4; ++r) {
                    int keyg = kb + 16 * s + 4 * g + r;
                    sm[s * 4 + r] = (keyg <= qrow) ? s4[s][r] * SCALE : -1e30f;
                }
        } else {
            #pragma unroll
            for (int s = 0; s < 4; ++s)
                #pragma unroll
                for (int r = 0; r < 4; ++r) sm[s * 4 + r] = s4[s][r] * SCALE;
        }
        float pm = sm[0];
        #pragma unroll
        for (int i = 1; i < 16; ++i) pm = fmaxf(pm, sm[i]);
        pm = fmaxf(pm, __shfl_xor(pm, 16));
        pm = fmaxf(pm, __shfl_xor(pm, 32));
        float mn = fmaxf(m, pm);
        float es = __expf(m - mn);
        float p[16], ps = 0.f;
        #pragma unroll
        for (int i = 0; i < 16; ++i) { p[i] = __expf(sm[i] - mn); ps += p[i]; }
        ps += __shfl_xor(ps, 16);
        ps += __shfl_xor(ps, 32);
        l = l * es + ps;
        m = mn;
        #pragma unroll
        for (int t = 0; t < 4; ++t)
            #pragma unroll
            for (int r = 0; r < 4; ++r) accO[t][r] *= es;

        short8 pf0, pf1;
        #pragma unroll
        for (int j = 0; j < 4; ++j) {
            pf0[j]     = (short)bf16rne(p[0 * 4 + j]);
            pf0[j + 4] = (short)bf16rne(p[1 * 4 + j]);
            pf1[j]     = (short)bf16rne(p[2 * 4 + j]);
            pf1[j + 4] = (short)bf16rne(p[3 * 4 + j]);
        }

        #pragma unroll
        for (int t = 0; t < 4; ++t) {
            const int h = 16 * t + n;
            const ushort* vb = &VtL[h << 6];
            union { int2 d[2]; short8 v; } u0, u1;
            u0.d[0] = *(const int2*)(vb + ((4 * g) ^ (csw << 3)));
            u0.d[1] = *(const int2*)(vb + ((16 + 4 * g) ^ (csw << 3)));
            u1.d[0] = *(const int2*)(vb + ((32 + 4 * g) ^ (csw << 3)));
            u1.d[1] = *(const int2*)(vb + ((48 + 4 * g) ^ (csw << 3)));
            accO[t] = __builtin_amdgcn_mfma_f32_16x16x32_bf16(u0.v, pf0, accO[t], 0, 0, 0);
            accO[t] = __builtin_amdgcn_mfma_f32_16x16x32_bf16(u1.v, pf1, accO[t], 0, 0, 0);
        }
    }

    // ---- write partials (unnormalized) ----
    const size_t brow = (size_t)b * TT + qrow;
    float* pa = Pacc + ((size_t)sp * NROWS + brow) * 64 + 4 * g;
    #pragma unroll
    for (int t = 0; t < 4; ++t)
        *(f32x4*)(pa + 16 * t) = accO[t];
    if (g == 0) {
        Pm[(size_t)sp * NROWS + brow] = m;
        Pl[(size_t)sp * NROWS + brow] = l;
    }
}

// ---------------------------------------------------------------------------
// Kernel C: merge SPLIT partials (unchanged).
// ---------------------------------------------------------------------------
__global__ __launch_bounds__(256) void combine_kernel(
        const float* __restrict__ Pacc, const float* __restrict__ Pm,
        const float* __restrict__ Pl, float* __restrict__ out) {
    const int u    = blockIdx.x * 256 + threadIdx.x;   // 0..65535
    const int row  = u >> 2;
    const int quad = u & 3;

    float ms[SPLIT], ls[SPLIT], M = -1e30f;
    #pragma unroll
    for (int s = 0; s < SPLIT; ++s) {
        ms[s] = Pm[(size_t)s * NROWS + row];
        ls[s] = Pl[(size_t)s * NROWS + row];
        M = fmaxf(M, ms[s]);
    }
    float wgt[SPLIT], den = 0.f;
    #pragma unroll
    for (int s = 0; s < SPLIT; ++s) {
        wgt[s] = __expf(ms[s] - M);
        den += wgt[s] * ls[s];
    }
    const float inv = 1.0f / den;

    float4 o[4];
    #pragma unroll
    for (int i = 0; i < 4; ++i) o[i] = make_float4(0.f, 0.f, 0.f, 0.f);
    #pragma unroll
    for (int s = 0; s < SPLIT; ++s) {
        const float4* a = (const float4*)(Pacc + ((size_t)s * NROWS + row) * 64 + quad * 16);
        #pragma unroll
        for (int i = 0; i < 4; ++i) {
            float4 v = a[i];
            o[i].x += wgt[s] * v.x; o[i].y += wgt[s] * v.y;
            o[i].z += wgt[s] * v.z; o[i].w += wgt[s] * v.w;
        }
    }
    float4* op = (float4*)(out + (size_t)row * 64 + quad * 16);
    #pragma unroll
    for (int i = 0; i < 4; ++i)
        op[i] = make_float4(o[i].x * inv, o[i].y * inv, o[i].z * inv, o[i].w * inv);
}

// ---------------------------------------------------------------------------
extern "C" void kernel_launch(void* const* d_in, const int* in_sizes, int n_in,
                              void* d_out, int out_size, void* d_ws, size_t ws_size,
                              hipStream_t stream) {
    const float* x  = (const float*)d_in[0];
    const float* Wq = (const float*)d_in[1];
    const float* Wk = (const float*)d_in[2];
    const float* Wv = (const float*)d_in[3];
    float* outp = (float*)d_out;

    float*  Qw   = (float*)d_ws;                        // 4 MB
    ushort* KhiP = (ushort*)(Qw + (size_t)NROWS * HH);  // 2 MB
    ushort* KloP = KhiP + (size_t)NROWS * HH;           // 2 MB
    ushort* VtP  = KloP + (size_t)NROWS * HH;           // 2 MB
    ushort* WpHi = VtP + (size_t)NROWS * HH;            // 384 KB
    ushort* WpLo = WpHi + (size_t)3 * 64 * 1024;        // 384 KB
    float*  Pacc = (float*)(WpLo + (size_t)3 * 64 * 1024);      // 16 MB
    float*  Pm   = Pacc + (size_t)SPLIT * NROWS * HH;           // 256 KB
    float*  Pl   = Pm + (size_t)SPLIT * NROWS;                  // 256 KB

    wprep_kernel<<<48, 256, 0, stream>>>(Wq, Wk, Wv, WpHi, WpLo);
    qkv_kernel<<<NROWS / 32, 256, 0, stream>>>(x, WpHi, WpLo, Qw, KhiP, KloP, VtP);
    attn_kernel<<<dim3(64 * SPLIT, BB), 128, 0, stream>>>(Qw, KhiP, KloP, VtP,
                                                          Pacc, Pm, Pl);
    combine_kernel<<<NROWS * 4 / 256, 256, 0, stream>>>(Pacc, Pm, Pl, outp);
}

// Round 12
// 72.033 us; speedup vs baseline: 1.2780x; 1.1183x over previous
//
#include <hip/hip_runtime.h>
#include <hip/hip_bf16.h>

// Head: B=8, T=2048, D=1024, H=64, fp32 in/out.
#define BB 8
#define TT 2048
#define DD 1024
#define HH 64
#define NROWS (BB*TT)
#define SCALE 45.25483399593904f   // sqrt(2048)
#define SPLIT 4                    // flash split-K factor

typedef __attribute__((ext_vector_type(8))) short short8;
typedef __attribute__((ext_vector_type(4))) float f32x4;

__device__ inline ushort bf16rne(float f) {
    unsigned u = __float_as_uint(f);
    return (ushort)((u + 0x7fffu + ((u >> 16) & 1u)) >> 16);
}
__device__ inline void bfsplit(float f, ushort& hi, ushort& lo) {
    hi = bf16rne(f);
    float fh = __uint_as_float(((unsigned)hi) << 16);
    lo = bf16rne(f - fh);
}
__device__ inline void split_pack8(const float* v, int4& h4, int4& l4) {
    ushort h[8], l[8];
    #pragma unroll
    for (int j = 0; j < 8; ++j) bfsplit(v[j], h[j], l[j]);
    h4 = make_int4((int)(h[0] | ((unsigned)h[1] << 16)), (int)(h[2] | ((unsigned)h[3] << 16)),
                   (int)(h[4] | ((unsigned)h[5] << 16)), (int)(h[6] | ((unsigned)h[7] << 16)));
    l4 = make_int4((int)(l[0] | ((unsigned)l[1] << 16)), (int)(l[2] | ((unsigned)l[3] << 16)),
                   (int)(l[4] | ((unsigned)l[5] << 16)), (int)(l[6] | ((unsigned)l[7] << 16)));
}

// async global->LDS, 16B per lane. LDS dest = wave-uniform base + lane*16.
__device__ inline void gload_lds16(const void* g, void* l) {
    __builtin_amdgcn_global_load_lds(
        (const __attribute__((address_space(1))) unsigned int*)(uintptr_t)(g),
        (__attribute__((address_space(3))) unsigned int*)(uintptr_t)(l),
        16, 0, 0);
}

// ---------------------------------------------------------------------------
// Kernel P: W prep — r9-PROVEN layout (BK=64 chunk-major, octet^(col&7)):
//   Wp[c][col][g8][j] = W[c*64 + (g8^(col&7))*8 + j][col&63], col = m*64+nn.
// (r11's BK=32 ^(col&3) variant measured 2.6M bank conflicts; reverted.)
// ---------------------------------------------------------------------------
__global__ __launch_bounds__(256) void wprep_kernel(
        const float* __restrict__ Wq, const float* __restrict__ Wk,
        const float* __restrict__ Wv,
        ushort* __restrict__ WpHi, ushort* __restrict__ WpLo) {
    __shared__ float ws[64 * 65];
    const int m = blockIdx.x >> 4;      // matrix 0..2
    const int c = blockIdx.x & 15;      // k-chunk 0..15
    const float* W = (m == 0) ? Wq : (m == 1) ? Wk : Wv;
    const int tid = threadIdx.x;

    #pragma unroll
    for (int p = 0; p < 4; ++p) {
        int i = tid + p * 256;
        int r = i >> 4, q4 = i & 15;
        float4 v = *(const float4*)(W + (size_t)(c * 64 + r) * 64 + q4 * 4);
        ws[r * 65 + q4 * 4 + 0] = v.x;
        ws[r * 65 + q4 * 4 + 1] = v.y;
        ws[r * 65 + q4 * 4 + 2] = v.z;
        ws[r * 65 + q4 * 4 + 3] = v.w;
    }
    __syncthreads();

    #pragma unroll
    for (int p = 0; p < 2; ++p) {
        int gi = tid + p * 256;
        int nn = gi >> 3, g8 = gi & 7;
        int o  = g8 ^ (nn & 7);
        float v[8];
        #pragma unroll
        for (int j = 0; j < 8; ++j) v[j] = ws[(o * 8 + j) * 65 + nn];
        int4 h4, l4; split_pack8(v, h4, l4);
        size_t base = (size_t)c * 12288 + (size_t)(m * 64 + nn) * 64 + g8 * 8;
        *(int4*)(WpHi + base) = h4;
        *(int4*)(WpLo + base) = l4;
    }
}

// ---------------------------------------------------------------------------
// Kernel A: QKV via MFMA 16x16x32 bf16, 3-pass split precision.
// r12: attack the measured per-XCD L2-BW ceiling on W re-reads:
//   - BM=64, 512-thread blocks, grid 256 (1 block/CU) -> W traffic HALVED
//     (196 MB total, ~1 TB/s/XCD at target time, under the 4.3 ceiling).
//   - BK=64, r9-proven swizzle (0 conflicts), B via global_load_lds DMA.
//   - One barrier/chunk pipeline: B dbuf (2x48KB) + A dbuf (2x16KB) = 128KB
//     LDS; DMA(c+1) issued before compute(c); x depth-2 reg prefetch.
// ---------------------------------------------------------------------------
__global__ __launch_bounds__(512) void qkv_kernel(
        const float* __restrict__ x,
        const ushort* __restrict__ WpHi, const ushort* __restrict__ WpLo,
        float* __restrict__ Qo, ushort* __restrict__ KhiP,
        ushort* __restrict__ KloP, ushort* __restrict__ VtP) {
    __shared__ ushort Ahi[2][64 * 64], Alo[2][64 * 64];     // 8 KiB per buf
    __shared__ ushort Bhi[2][192 * 64], Blo[2][192 * 64];   // 24 KiB per buf
    const int tid  = threadIdx.x;
    const int lane = tid & 63;
    const int w    = tid >> 6;           // wave 0..7
    const int wm   = w >> 2;             // m-half (32 rows)
    const int wn   = w & 3;              // n-quarter (48 cols)
    const int n15  = lane & 15;
    const int g    = lane >> 4;
    const int csw  = n15 & 7;
    const int row0 = blockIdx.x * 64;

    f32x4 acc[2][3];
    #pragma unroll
    for (int ms = 0; ms < 2; ++ms)
        #pragma unroll
        for (int nt = 0; nt < 3; ++nt) acc[ms][nt] = (f32x4)0.f;

    // A-stage geometry: thread owns (row ar, octet aoc) — 8 floats per chunk
    const int ar = tid >> 3, aoc = tid & 7;
    const float* xrow = x + (size_t)(row0 + ar) * 1024 + aoc * 8;
    const int adi = ar * 64 + ((aoc ^ (ar & 7)) << 3);

    // B DMA: 24 chunks of 1KB per array; wave w owns chunks w*3..w*3+2
    const ushort* wsh = WpHi + (size_t)lane * 8;
    const ushort* wsl = WpLo + (size_t)lane * 8;

    // ---- prologue: A(0), B(0) -> buf0; xA=x(1), xB=x(2) ----
    {
        float v[8];
        *(float4*)v       = *(const float4*)(xrow);
        *(float4*)(v + 4) = *(const float4*)(xrow + 4);
        int4 h4, l4; split_pack8(v, h4, l4);
        *(int4*)&Ahi[0][adi] = h4;
        *(int4*)&Alo[0][adi] = l4;
    }
    #pragma unroll
    for (int p = 0; p < 3; ++p) {
        int j = w * 3 + p;
        gload_lds16(wsh + j * 512, &Bhi[0][j * 512]);
        gload_lds16(wsl + j * 512, &Blo[0][j * 512]);
    }
    float xA[8], xB[8];
    *(float4*)(xA)     = *(const float4*)(xrow + 64);
    *(float4*)(xA + 4) = *(const float4*)(xrow + 68);
    *(float4*)(xB)     = *(const float4*)(xrow + 128);
    *(float4*)(xB + 4) = *(const float4*)(xrow + 132);
    __syncthreads();

    int cur = 0;
    for (int c = 0; c < 16; ++c) {
        // ---- prefetch x(c+3), clamped ----
        const int c3 = (c + 3 < 16) ? c + 3 : 15;
        float xN[8];
        *(float4*)(xN)     = *(const float4*)(xrow + c3 * 64);
        *(float4*)(xN + 4) = *(const float4*)(xrow + c3 * 64 + 4);
        // ---- issue B DMA for chunk c+1 (clamped) into buf^1 ----
        const int c1 = (c + 1 < 16) ? c + 1 : 15;
        {
            const ushort* sh = wsh + (size_t)c1 * 12288;
            const ushort* sl = wsl + (size_t)c1 * 12288;
            #pragma unroll
            for (int p = 0; p < 3; ++p) {
                int j = w * 3 + p;
                gload_lds16(sh + j * 512, &Bhi[cur ^ 1][j * 512]);
                gload_lds16(sl + j * 512, &Blo[cur ^ 1][j * 512]);
            }
        }
        // ---- convert xA (chunk c+1) into A buf^1 ----
        {
            int4 h4, l4; split_pack8(xA, h4, l4);
            *(int4*)&Ahi[cur ^ 1][adi] = h4;
            *(int4*)&Alo[cur ^ 1][adi] = l4;
        }
        // ---- compute chunk c from buf[cur] ----
        #pragma unroll
        for (int kh = 0; kh < 2; ++kh) {
            short8 afh[2], afl[2], bfh[3], bfl[3];
            #pragma unroll
            for (int ms = 0; ms < 2; ++ms) {
                int ao = (wm * 32 + ms * 16 + n15) * 64 + (((4 * kh + g) ^ csw) << 3);
                afh[ms] = *(const short8*)&Ahi[cur][ao];
                afl[ms] = *(const short8*)&Alo[cur][ao];
            }
            #pragma unroll
            for (int nt = 0; nt < 3; ++nt) {
                int bo = (wn * 48 + nt * 16 + n15) * 64 + (((4 * kh + g) ^ csw) << 3);
                bfh[nt] = *(const short8*)&Bhi[cur][bo];
                bfl[nt] = *(const short8*)&Blo[cur][bo];
            }
            #pragma unroll
            for (int nt = 0; nt < 3; ++nt)
                #pragma unroll
                for (int ms = 0; ms < 2; ++ms) {
                    acc[ms][nt] = __builtin_amdgcn_mfma_f32_16x16x32_bf16(
                        afh[ms], bfh[nt], acc[ms][nt], 0, 0, 0);
                    acc[ms][nt] = __builtin_amdgcn_mfma_f32_16x16x32_bf16(
                        afl[ms], bfh[nt], acc[ms][nt], 0, 0, 0);
                    acc[ms][nt] = __builtin_amdgcn_mfma_f32_16x16x32_bf16(
                        afh[ms], bfl[nt], acc[ms][nt], 0, 0, 0);
                }
        }
        __syncthreads();                 // ONE barrier: drains DMA + A writes
        #pragma unroll
        for (int j = 0; j < 8; ++j) { xA[j] = xB[j]; xB[j] = xN[j]; }
        cur ^= 1;
    }

    // ---- epilogue: row = row0+wm*32+ms*16+4g+r, col = wn*48+nt*16+n15 ----
    const int b  = row0 >> 11;
    const int t0 = row0 & 2047;
    #pragma unroll
    for (int nt = 0; nt < 3; ++nt) {
        const int col = wn * 48 + nt * 16 + n15;
        const int mat = col >> 6;        // wave-uniform per nt
        const int h   = col & 63;
        #pragma unroll
        for (int ms = 0; ms < 2; ++ms) {
            const int mb = row0 + wm * 32 + ms * 16 + 4 * g;
            if (mat == 0) {
                #pragma unroll
                for (int r = 0; r < 4; ++r)
                    Qo[(size_t)(mb + r) * 64 + h] = acc[ms][nt][r];
            } else if (mat == 1) {
                #pragma unroll
                for (int r = 0; r < 4; ++r) {
                    ushort hi, lo; bfsplit(acc[ms][nt][r], hi, lo);
                    KhiP[(size_t)(mb + r) * 64 + h] = hi;
                    KloP[(size_t)(mb + r) * 64 + h] = lo;
                }
            } else {
                ushort pk[4];
                #pragma unroll
                for (int r = 0; r < 4; ++r) pk[r] = bf16rne(acc[ms][nt][r]);
                const int tloc = t0 + wm * 32 + ms * 16 + 4 * g;
                *(uint2*)&VtP[((size_t)(b * 64 + h)) * 2048 + tloc] =
                    make_uint2(pk[0] | ((unsigned)pk[1] << 16),
                               pk[2] | ((unsigned)pk[3] << 16));
            }
        }
    }
}

// ---------------------------------------------------------------------------
// Kernel B: causal flash attention (r9, unchanged): MFMA + DMA-staged LDS +
// split-K x4 (2048 blocks, ~6 blocks/CU).
// ---------------------------------------------------------------------------
__global__ __launch_bounds__(128) void attn_kernel(
        const float* __restrict__ Q, const ushort* __restrict__ Khi,
        const ushort* __restrict__ Klo, const ushort* __restrict__ Vt,
        float* __restrict__ Pacc, float* __restrict__ Pm,
        float* __restrict__ Pl) {
    __shared__ ushort KhiL[64 * 64];   // [key][h ^ ((key&7)<<3)]
    __shared__ ushort KloL[64 * 64];
    __shared__ ushort VtL[64 * 64];    // [h][key ^ ((h&7)<<3)]
    const int tid  = threadIdx.x;
    const int lane = tid & 63;
    const int w    = tid >> 6;
    const int n    = lane & 15;
    const int g    = lane >> 4;
    const int b    = blockIdx.y;
    const int xx   = blockIdx.x;            // 0..255, heavy-first
    const int qt   = 63 - (xx >> 2);
    const int sp   = xx & 3;
    const int q0   = qt * 32;
    const int qmin = q0 + w * 16;
    const int qrow = qmin + n;
    const int csw  = n & 7;
    const int ntiles = (q0 >> 6) + 1;
    const int it0  = (ntiles * sp) >> 2;    // last split owns the diagonal
    const int it1  = (ntiles * (sp + 1)) >> 2;

    short8 qhi0, qhi1, qlo0, qlo1;
    {
        const float* qp = Q + ((size_t)b * TT + qrow) * HH + 8 * g;
        float v0[8], v1[8];
        *(float4*)(v0)     = *(const float4*)(qp);
        *(float4*)(v0 + 4) = *(const float4*)(qp + 4);
        *(float4*)(v1)     = *(const float4*)(qp + 32);
        *(float4*)(v1 + 4) = *(const float4*)(qp + 36);
        #pragma unroll
        for (int j = 0; j < 8; ++j) {
            ushort hi, lo;
            bfsplit(v0[j], hi, lo); qhi0[j] = (short)hi; qlo0[j] = (short)lo;
            bfsplit(v1[j], hi, lo); qhi1[j] = (short)hi; qlo1[j] = (short)lo;
        }
    }

    f32x4 accO[4];
    #pragma unroll
    for (int t = 0; t < 4; ++t) accO[t] = (f32x4)0.f;
    float m = -1e30f, l = 0.f;

    const ushort* gkh = Khi + (size_t)b * TT * HH;
    const ushort* gkl = Klo + (size_t)b * TT * HH;
    const ushort* gvt = Vt + (size_t)b * 64 * TT;

    const int crow = lane >> 3;             // row within 8-row chunk
    const int coct = lane & 7;              // LDS octet position

    for (int it = it0; it < it1; ++it) {
        const int kb = it * 64;
        __syncthreads();                    // prev compute done with LDS
        #pragma unroll
        for (int p = 0; p < 4; ++p) {
            const int cc  = w * 4 + p;      // chunk 0..7
            const int row = (cc << 3) + crow;
            const int soc = coct ^ (row & 7);
            gload_lds16(gkh + (size_t)(kb + row) * HH + (soc << 3), &KhiL[cc << 9]);
            gload_lds16(gkl + (size_t)(kb + row) * HH + (soc << 3), &KloL[cc << 9]);
            gload_lds16(gvt + (size_t)row * TT + kb + (soc << 3),   &VtL[cc << 9]);
        }
        __syncthreads();                    // drains vmcnt -> tiles ready

        f32x4 s4[4];
        #pragma unroll
        for (int s = 0; s < 4; ++s) {
            const int keyl = 16 * s + n;
            const ushort* kbase = &KhiL[keyl << 6];
            const ushort* lbase = &KloL[keyl << 6];
            short8 kh0 = *(const short8*)(kbase + ((g ^ csw) << 3));
            short8 kh1 = *(const short8*)(kbase + (((4 + g) ^ csw) << 3));
            short8 kl0 = *(const short8*)(lbase + ((g ^ csw) << 3));
            short8 kl1 = *(const short8*)(lbase + (((4 + g) ^ csw) << 3));
            f32x4 a = (f32x4)0.f;
            a = __builtin_amdgcn_mfma_f32_16x16x32_bf16(kh0, qhi0, a, 0, 0, 0);
            a = __builtin_amdgcn_mfma_f32_16x16x32_bf16(kh1, qhi1, a, 0, 0, 0);
            a = __builtin_amdgcn_mfma_f32_16x16x32_bf16(kl0, qhi0, a, 0, 0, 0);
            a = __builtin_amdgcn_mfma_f32_16x16x32_bf16(kl1, qhi1, a, 0, 0, 0);
            a = __builtin_amdgcn_mfma_f32_16x16x32_bf16(kh0, qlo0, a, 0, 0, 0);
            a = __builtin_amdgcn_mfma_f32_16x16x32_bf16(kh1, qlo1, a, 0, 0, 0);
            s4[s] = a;
        }

        float sm[16];
        if (kb + 63 > qmin) {               // diagonal tile only
            #pragma unroll
            for (int s = 0; s < 4; ++s)
                #pragma unroll
                for (int r = 0; r < 4; ++r) {
                    int keyg = kb + 16 * s + 4 * g + r;
                    sm[s * 4 + r] = (keyg <= qrow) ? s4[s][r] * SCALE : -1e30f;
                }
        } else {
            #pragma unroll
            for (int s = 0; s < 4; ++s)
                #pragma unroll
                for (int r = 0; r < 4; ++r) sm[s * 4 + r] = s4[s][r] * SCALE;
        }
        float pm = sm[0];
        #pragma unroll
        for (int i = 1; i < 16; ++i) pm = fmaxf(pm, sm[i]);
        pm = fmaxf(pm, __shfl_xor(pm, 16));
        pm = fmaxf(pm, __shfl_xor(pm, 32));
        float mn = fmaxf(m, pm);
        float es = __expf(m - mn);
        float p[16], ps = 0.f;
        #pragma unroll
        for (int i = 0; i < 16; ++i) { p[i] = __expf(sm[i] - mn); ps += p[i]; }
        ps += __shfl_xor(ps, 16);
        ps += __shfl_xor(ps, 32);
        l = l * es + ps;
        m = mn;
        #pragma unroll
        for (int t = 0; t < 4; ++t)
            #pragma unroll
            for (int r = 0; r < 4; ++r) accO[t][r] *= es;

        short8 pf0, pf1;
        #pragma unroll
        for (int j = 0; j < 4; ++j) {
            pf0[j]     = (short)bf16rne(p[0 * 4 + j]);
            pf0[j + 4] = (short)bf16rne(p[1 * 4 + j]);
            pf1[j]     = (short)bf16rne(p[2 * 4 + j]);
            pf1[j + 4] = (short)bf16rne(p[3 * 4 + j]);
        }

        #pragma unroll
        for (int t = 0; t < 4; ++t) {
            const int h = 16 * t + n;
            const ushort* vb = &VtL[h << 6];
            union { int2 d[2]; short8 v; } u0, u1;
            u0.d[0] = *(const int2*)(vb + ((4 * g) ^ (csw << 3)));
            u0.d[1] = *(const int2*)(vb + ((16 + 4 * g) ^ (csw << 3)));
            u1.d[0] = *(const int2*)(vb + ((32 + 4 * g) ^ (csw << 3)));
            u1.d[1] = *(const int2*)(vb + ((48 + 4 * g) ^ (csw << 3)));
            accO[t] = __builtin_amdgcn_mfma_f32_16x16x32_bf16(u0.v, pf0, accO[t], 0, 0, 0);
            accO[t] = __builtin_amdgcn_mfma_f32_16x16x32_bf16(u1.v, pf1, accO[t], 0, 0, 0);
        }
    }

    // ---- write partials (unnormalized) ----
    const size_t brow = (size_t)b * TT + qrow;
    float* pa = Pacc + ((size_t)sp * NROWS + brow) * 64 + 4 * g;
    #pragma unroll
    for (int t = 0; t < 4; ++t)
        *(f32x4*)(pa + 16 * t) = accO[t];
    if (g == 0) {
        Pm[(size_t)sp * NROWS + brow] = m;
        Pl[(size_t)sp * NROWS + brow] = l;
    }
}

// ---------------------------------------------------------------------------
// Kernel C: merge SPLIT partials (unchanged).
// ---------------------------------------------------------------------------
__global__ __launch_bounds__(256) void combine_kernel(
        const float* __restrict__ Pacc, const float* __restrict__ Pm,
        const float* __restrict__ Pl, float* __restrict__ out) {
    const int u    = blockIdx.x * 256 + threadIdx.x;   // 0..65535
    const int row  = u >> 2;
    const int quad = u & 3;

    float ms[SPLIT], ls[SPLIT], M = -1e30f;
    #pragma unroll
    for (int s = 0; s < SPLIT; ++s) {
        ms[s] = Pm[(size_t)s * NROWS + row];
        ls[s] = Pl[(size_t)s * NROWS + row];
        M = fmaxf(M, ms[s]);
    }
    float wgt[SPLIT], den = 0.f;
    #pragma unroll
    for (int s = 0; s < SPLIT; ++s) {
        wgt[s] = __expf(ms[s] - M);
        den += wgt[s] * ls[s];
    }
    const float inv = 1.0f / den;

    float4 o[4];
    #pragma unroll
    for (int i = 0; i < 4; ++i) o[i] = make_float4(0.f, 0.f, 0.f, 0.f);
    #pragma unroll
    for (int s = 0; s < SPLIT; ++s) {
        const float4* a = (const float4*)(Pacc + ((size_t)s * NROWS + row) * 64 + quad * 16);
        #pragma unroll
        for (int i = 0; i < 4; ++i) {
            float4 v = a[i];
            o[i].x += wgt[s] * v.x; o[i].y += wgt[s] * v.y;
            o[i].z += wgt[s] * v.z; o[i].w += wgt[s] * v.w;
        }
    }
    float4* op = (float4*)(out + (size_t)row * 64 + quad * 16);
    #pragma unroll
    for (int i = 0; i < 4; ++i)
        op[i] = make_float4(o[i].x * inv, o[i].y * inv, o[i].z * inv, o[i].w * inv);
}

// ---------------------------------------------------------------------------
extern "C" void kernel_launch(void* const* d_in, const int* in_sizes, int n_in,
                              void* d_out, int out_size, void* d_ws, size_t ws_size,
                              hipStream_t stream) {
    const float* x  = (const float*)d_in[0];
    const float* Wq = (const float*)d_in[1];
    const float* Wk = (const float*)d_in[2];
    const float* Wv = (const float*)d_in[3];
    float* outp = (float*)d_out;

    float*  Qw   = (float*)d_ws;                        // 4 MB
    ushort* KhiP = (ushort*)(Qw + (size_t)NROWS * HH);  // 2 MB
    ushort* KloP = KhiP + (size_t)NROWS * HH;           // 2 MB
    ushort* VtP  = KloP + (size_t)NROWS * HH;           // 2 MB
    ushort* WpHi = VtP + (size_t)NROWS * HH;            // 384 KB
    ushort* WpLo = WpHi + (size_t)3 * 64 * 1024;        // 384 KB
    float*  Pacc = (float*)(WpLo + (size_t)3 * 64 * 1024);      // 16 MB
    float*  Pm   = Pacc + (size_t)SPLIT * NROWS * HH;           // 256 KB
    float*  Pl   = Pm + (size_t)SPLIT * NROWS;                  // 256 KB

    wprep_kernel<<<48, 256, 0, stream>>>(Wq, Wk, Wv, WpHi, WpLo);
    qkv_kernel<<<NROWS / 64, 512, 0, stream>>>(x, WpHi, WpLo, Qw, KhiP, KloP, VtP);
    attn_kernel<<<dim3(64 * SPLIT, BB), 128, 0, stream>>>(Qw, KhiP, KloP, VtP,
                                                          Pacc, Pm, Pl);
    combine_kernel<<<NROWS * 4 / 256, 256, 0, stream>>>(Pacc, Pm, Pl, outp);
}